// Round 4
// baseline (4059.664 us; speedup 1.0000x reference)
//
#include <hip/hip_runtime.h>

#define GB   16          // samples per block
#define B_SZ 16384

// ---------- one-time weight transpose: dst[C][R] = src[R][C]^T ----------
__global__ __launch_bounds__(256) void k_transpose(const float* __restrict__ src,
                                                   float* __restrict__ dst,
                                                   int R, int C) {
    __shared__ float tile[32][33];
    int bx = blockIdx.x * 32, by = blockIdx.y * 32;
    int tx = threadIdx.x & 31, ty = threadIdx.x >> 5;   // 256 threads: ty 0..7
#pragma unroll
    for (int r = ty; r < 32; r += 8) {
        int gr = by + r, gc = bx + tx;
        if (gr < R && gc < C) tile[r][tx] = src[gr * C + gc];
    }
    __syncthreads();
#pragma unroll
    for (int r = ty; r < 32; r += 8) {
        int gr = bx + r, gc = by + tx;
        if (gr < C && gc < R) dst[gr * R + gc] = tile[tx][r];
    }
}

// ---------- fully fused SNN: all 15 steps, all 5 layers, one dispatch ----------
// Thread t owns output neuron j=t (j=t&127 for layer 5) across GB samples.
// Spikes broadcast via LDS [i][g]; membranes in registers; weights from L2.
// Accumulation: ascending-i f32 FMA chain == bit-exact vs round-0 kernel.
__global__ __launch_bounds__(256, 3) void k_snn(
    const float* __restrict__ x,   const float* __restrict__ W1, const float* __restrict__ b1,
    const float* __restrict__ Wt2, const float* __restrict__ b2,
    const float* __restrict__ Wt3, const float* __restrict__ b3,
    const float* __restrict__ Wt4, const float* __restrict__ b4,
    const float* __restrict__ Wt5, const float* __restrict__ b5,
    const float* __restrict__ W6,  const float* __restrict__ b6,
    float* __restrict__ out)
{
    __shared__ __align__(16) float slds[256][20];   // [input idx][sample], pad 20 for aligned float4
    __shared__ float w6l[3][128];
    __shared__ float xl[GB][8];
    const int t  = threadIdx.x;
    const int s0 = blockIdx.x * GB;

    if (t < 384) ((float*)w6l)[t] = W6[t];
    if (t < GB * 8) { int g = t >> 3, c = t & 7; xl[g][c] = (c < 6) ? x[(s0 + g) * 6 + c] : 0.f; }
    __syncthreads();

    // layer-1 input current (constant across timesteps), j = t, sequential i
    float w1r[6];
#pragma unroll
    for (int i = 0; i < 6; ++i) w1r[i] = W1[t * 6 + i];
    const float b1v = b1[t], b2v = b2[t], b3v = b3[t], b4v = b4[t], b5v = b5[t & 127];

    float cur1[GB];
#pragma unroll
    for (int g = 0; g < GB; ++g) {
        float s = 0.f;
#pragma unroll
        for (int i = 0; i < 6; ++i) s = fmaf(xl[g][i], w1r[i], s);
        cur1[g] = s + b1v;
    }

    float m1[GB], m2[GB], m3[GB], m4[GB], m5h[8];
#pragma unroll
    for (int g = 0; g < GB; ++g) { m1[g] = 0.f; m2[g] = 0.f; m3[g] = 0.f; m4[g] = 0.f; }
#pragma unroll
    for (int q = 0; q < 8; ++q) m5h[q] = 0.f;

    const int half = t >> 7;                 // layer-5: which 8-sample half
    const int j5   = t & 127;
    const int og = t / 3, ok = t - og * 3;   // layer-6 owner mapping (t<48)
    const float b6v = (t < 48) ? b6[ok] : 0.f;
    float accout = 0.f;

    for (int step = 0; step < 15; ++step) {
        __syncthreads();                     // prior step's L6 readers done before L1 writes
        // ---- layer-1 LIF ----
#pragma unroll
        for (int g = 0; g < GB; ++g) {
            float mp = m1[g];
            float mn = fmaf(0.9f, mp, cur1[g]) - (mp > 1.0f ? 1.0f : 0.0f);
            m1[g] = mn;
            slds[t][g] = (mn > 1.0f) ? 1.0f : 0.0f;
        }
        __syncthreads();

        // ---- 256->256 fused matmul + LIF (bit-exact sequential i) ----
#define MM256_LIF(WT, BIAS, BETA, MARR)                                          \
        {                                                                        \
            float acc[GB];                                                       \
            _Pragma("unroll") for (int g = 0; g < GB; ++g) acc[g] = 0.f;         \
            const float* wp = WT + t;                                            \
            _Pragma("unroll 4") for (int i = 0; i < 256; ++i) {                  \
                float w = wp[i * 256];                                           \
                const float4* sr = (const float4*)&slds[i][0];                   \
                float4 sa = sr[0], sb = sr[1], sc = sr[2], sd = sr[3];           \
                acc[0]  = fmaf(sa.x, w, acc[0]);  acc[1]  = fmaf(sa.y, w, acc[1]);   \
                acc[2]  = fmaf(sa.z, w, acc[2]);  acc[3]  = fmaf(sa.w, w, acc[3]);   \
                acc[4]  = fmaf(sb.x, w, acc[4]);  acc[5]  = fmaf(sb.y, w, acc[5]);   \
                acc[6]  = fmaf(sb.z, w, acc[6]);  acc[7]  = fmaf(sb.w, w, acc[7]);   \
                acc[8]  = fmaf(sc.x, w, acc[8]);  acc[9]  = fmaf(sc.y, w, acc[9]);   \
                acc[10] = fmaf(sc.z, w, acc[10]); acc[11] = fmaf(sc.w, w, acc[11]);  \
                acc[12] = fmaf(sd.x, w, acc[12]); acc[13] = fmaf(sd.y, w, acc[13]);  \
                acc[14] = fmaf(sd.z, w, acc[14]); acc[15] = fmaf(sd.w, w, acc[15]);  \
            }                                                                    \
            __syncthreads();                                                     \
            _Pragma("unroll") for (int g = 0; g < GB; ++g) {                     \
                float cur = acc[g] + BIAS;                                       \
                float mp  = MARR[g];                                             \
                float mn  = fmaf(BETA, mp, cur) - (mp > 1.0f ? 1.0f : 0.0f);     \
                MARR[g] = mn;                                                    \
                slds[t][g] = (mn > 1.0f) ? 1.0f : 0.0f;                          \
            }                                                                    \
            __syncthreads();                                                     \
        }

        MM256_LIF(Wt2, b2v, 0.88f, m2)
        MM256_LIF(Wt3, b3v, 0.86f, m3)
        MM256_LIF(Wt4, b4v, 0.84f, m4)

        // ---- layer-5: 256 -> 128 (each thread: 1 neuron x 8 samples) ----
        {
            float acc[8];
#pragma unroll
            for (int q = 0; q < 8; ++q) acc[q] = 0.f;
            const float* wp = Wt5 + j5;
            const int gb4 = half * 2;        // float4 offset: half*8 floats
#pragma unroll 4
            for (int i = 0; i < 256; ++i) {
                float w = wp[i * 128];
                const float4* sr = (const float4*)&slds[i][0];
                float4 sa = sr[gb4], sb = sr[gb4 + 1];
                acc[0] = fmaf(sa.x, w, acc[0]); acc[1] = fmaf(sa.y, w, acc[1]);
                acc[2] = fmaf(sa.z, w, acc[2]); acc[3] = fmaf(sa.w, w, acc[3]);
                acc[4] = fmaf(sb.x, w, acc[4]); acc[5] = fmaf(sb.y, w, acc[5]);
                acc[6] = fmaf(sb.z, w, acc[6]); acc[7] = fmaf(sb.w, w, acc[7]);
            }
            __syncthreads();
#pragma unroll
            for (int q = 0; q < 8; ++q) {
                int g = half * 8 + q;
                float cur = acc[q] + b5v;
                float mp  = m5h[q];
                float mn  = fmaf(0.82f, mp, cur) - (mp > 1.0f ? 1.0f : 0.0f);
                m5h[q] = mn;
                slds[j5][g] = (mn > 1.0f) ? 1.0f : 0.0f;
            }
            __syncthreads();
        }

        // ---- layer-6: 128 -> 3, accumulate over steps ----
        if (t < 48) {
            float s = 0.f;
#pragma unroll 4
            for (int i = 0; i < 128; ++i) s = fmaf(slds[i][og], w6l[ok][i], s);
            float ov = s + b6v;
            accout = (step == 0) ? ov : (accout + ov);
        }
    }

    if (t < 48) out[(s0 + og) * 3 + ok] = accout / 15.0f;
}

extern "C" void kernel_launch(void* const* d_in, const int* in_sizes, int n_in,
                              void* d_out, int out_size, void* d_ws, size_t ws_size,
                              hipStream_t stream) {
    const float* x  = (const float*)d_in[0];
    const float* W1 = (const float*)d_in[1];
    const float* b1 = (const float*)d_in[2];
    const float* W2 = (const float*)d_in[3];
    const float* b2 = (const float*)d_in[4];
    const float* W3 = (const float*)d_in[5];
    const float* b3 = (const float*)d_in[6];
    const float* W4 = (const float*)d_in[7];
    const float* b4 = (const float*)d_in[8];
    const float* W5 = (const float*)d_in[9];
    const float* b5 = (const float*)d_in[10];
    const float* W6 = (const float*)d_in[11];
    const float* b6 = (const float*)d_in[12];
    float* out = (float*)d_out;

    float* ws  = (float*)d_ws;
    float* Wt2 = ws;                 // [256][256]
    float* Wt3 = Wt2 + 65536;        // [256][256]
    float* Wt4 = Wt3 + 65536;        // [256][256]
    float* Wt5 = Wt4 + 65536;        // [256][128]
    size_t need = (size_t)(65536 * 3 + 32768) * sizeof(float);
    if (ws_size < need) return;

    k_transpose<<<dim3(8, 8), 256, 0, stream>>>(W2, Wt2, 256, 256);
    k_transpose<<<dim3(8, 8), 256, 0, stream>>>(W3, Wt3, 256, 256);
    k_transpose<<<dim3(8, 8), 256, 0, stream>>>(W4, Wt4, 256, 256);
    k_transpose<<<dim3(8, 4), 256, 0, stream>>>(W5, Wt5, 128, 256);
    k_snn<<<B_SZ / GB, 256, 0, stream>>>(x, W1, b1, Wt2, b2, Wt3, b3,
                                         Wt4, b4, Wt5, b5, W6, b6, out);
}

// Round 7
// 2640.321 us; speedup vs baseline: 1.5376x; 1.5376x over previous
//
#include <hip/hip_runtime.h>

#define B_SZ 16384

// ---------- one-time weight transpose: dst[C][R] = src[R][C]^T ----------
__global__ __launch_bounds__(256) void k_transpose(const float* __restrict__ src,
                                                   float* __restrict__ dst,
                                                   int R, int C) {
    __shared__ float tile[32][33];
    int bx = blockIdx.x * 32, by = blockIdx.y * 32;
    int tx = threadIdx.x & 31, ty = threadIdx.x >> 5;
#pragma unroll
    for (int r = ty; r < 32; r += 8) {
        int gr = by + r, gc = bx + tx;
        if (gr < R && gc < C) tile[r][tx] = src[gr * C + gc];
    }
    __syncthreads();
#pragma unroll
    for (int r = ty; r < 32; r += 8) {
        int gr = bx + r, gc = by + tx;
        if (gr < C && gc < R) dst[gr * R + gc] = tile[tx][r];
    }
}

// 256->256 matmul accumulate: thread owns (4 j, 4 g). Skipped when prev layer silent.
// Ascending-i f32 FMA chain per (j,g): bit-exact vs reference.
__device__ __forceinline__ void mm256(const float* __restrict__ WT,
                                      const float (*slds)[16],
                                      const int* flagrow, int q, int g0,
                                      float* acc) {
#pragma unroll
    for (int k = 0; k < 16; ++k) acc[k] = 0.f;
    int4 f = *(const int4*)flagrow;
    if ((f.x | f.y | f.z | f.w) == 0) return;          // silent input => acc = 0 exactly
    const float4* wp = (const float4*)WT + q;
#pragma unroll 4
    for (int i = 0; i < 256; ++i) {
        float4 w4 = wp[i * 64];                        // Wt[i][4q..4q+3], coalesced 16B/lane
        float4 s4 = *(const float4*)&slds[i][g0];      // spk[i][4g]: 4 bank-disjoint addrs/wave
        acc[0]  = fmaf(s4.x, w4.x, acc[0]);
        acc[1]  = fmaf(s4.y, w4.x, acc[1]);
        acc[2]  = fmaf(s4.z, w4.x, acc[2]);
        acc[3]  = fmaf(s4.w, w4.x, acc[3]);
        acc[4]  = fmaf(s4.x, w4.y, acc[4]);
        acc[5]  = fmaf(s4.y, w4.y, acc[5]);
        acc[6]  = fmaf(s4.z, w4.y, acc[6]);
        acc[7]  = fmaf(s4.w, w4.y, acc[7]);
        acc[8]  = fmaf(s4.x, w4.z, acc[8]);
        acc[9]  = fmaf(s4.y, w4.z, acc[9]);
        acc[10] = fmaf(s4.z, w4.z, acc[10]);
        acc[11] = fmaf(s4.w, w4.z, acc[11]);
        acc[12] = fmaf(s4.x, w4.w, acc[12]);
        acc[13] = fmaf(s4.y, w4.w, acc[13]);
        acc[14] = fmaf(s4.z, w4.w, acc[14]);
        acc[15] = fmaf(s4.w, w4.w, acc[15]);
    }
}

// LIF update + spike write for (4j,4g) ownership; returns any-spike predicate
__device__ __forceinline__ int lif4x4(float* m, const float* acc, const float* b4,
                                      float beta, float (*slds)[16], int j0, int g0) {
    int any = 0;
#pragma unroll
    for (int jj = 0; jj < 4; ++jj) {
        float4 sp;
#pragma unroll
        for (int gg = 0; gg < 4; ++gg) {
            int k = jj * 4 + gg;
            float cur = acc[k] + b4[jj];
            float mp  = m[k];
            float mn  = fmaf(beta, mp, cur) - (mp > 1.f ? 1.f : 0.f);
            m[k] = mn;
            int s1 = (mn > 1.f);
            any |= s1;
            ((float*)&sp)[gg] = s1 ? 1.f : 0.f;
        }
        *(float4*)&slds[j0 + jj][g0] = sp;
    }
    return any;
}

__global__ __launch_bounds__(256, 3) void k_snn(
    const float* __restrict__ x,   const float* __restrict__ W1, const float* __restrict__ b1,
    const float* __restrict__ Wt2, const float* __restrict__ b2,
    const float* __restrict__ Wt3, const float* __restrict__ b3,
    const float* __restrict__ Wt4, const float* __restrict__ b4,
    const float* __restrict__ Wt5, const float* __restrict__ b5,
    const float* __restrict__ W6,  const float* __restrict__ b6,
    float* __restrict__ out)
{
    __shared__ __align__(16) float slds[256][16];   // spikes [neuron][sample]
    __shared__ float w6l[3][128];
    __shared__ float xl[16][8];
    __shared__ __align__(16) int flags[5][4];       // [layer][wave] any-spike

    const int t    = threadIdx.x;
    const int s0   = blockIdx.x * 16;
    const int q    = t >> 2, r = t & 3;
    const int j0   = q * 4, g0 = r * 4;
    const int lane = t & 63, wvid = t >> 6;

    for (int k = t; k < 384; k += 256) ((float*)w6l)[k] = W6[k];   // all 384 loaded
    if (t < 128) { int g = t >> 3, c = t & 7; xl[g][c] = (c < 6) ? x[(s0 + g) * 6 + c] : 0.f; }
    __syncthreads();

    const float4 b2q = *(const float4*)&b2[j0];
    const float4 b3q = *(const float4*)&b3[j0];
    const float4 b4q = *(const float4*)&b4[j0];
    const float2 b5q = *(const float2*)&b5[q * 2];
    const int og = t / 3, ok = t - og * 3;
    const float b6v = (t < 48) ? b6[ok] : 0.f;

    // layer-1 input current (constant over steps), bias folded in
    float cur1[16];
#pragma unroll
    for (int jj = 0; jj < 4; ++jj) {
        float w1r[6];
#pragma unroll
        for (int k = 0; k < 6; ++k) w1r[k] = W1[(j0 + jj) * 6 + k];
        float bb = b1[j0 + jj];
#pragma unroll
        for (int gg = 0; gg < 4; ++gg) {
            float s = 0.f;
#pragma unroll
            for (int k = 0; k < 6; ++k) s = fmaf(xl[g0 + gg][k], w1r[k], s);
            cur1[jj * 4 + gg] = s + bb;
        }
    }

    float m1[16], m2[16], m3[16], m4[16], m5[8], acc[16];
#pragma unroll
    for (int k = 0; k < 16; ++k) { m1[k] = 0.f; m2[k] = 0.f; m3[k] = 0.f; m4[k] = 0.f; }
#pragma unroll
    for (int k = 0; k < 8; ++k) m5[k] = 0.f;
    float accout = 0.f;
    const float zb[4] = {0.f, 0.f, 0.f, 0.f};

#pragma unroll 1
    for (int step = 0; step < 15; ++step) {
        __syncthreads();                      // prev step's L6 reads done before L1 writes

        // ---- layer 1 LIF (bias already in cur1) ----
        {
            int any = lif4x4(m1, cur1, zb, 0.9f, slds, j0, g0);
            unsigned long long bl = __ballot(any);
            if (lane == 0) flags[0][wvid] = (bl != 0ULL) ? 1 : 0;
        }
        __syncthreads();

        // ---- layer 2 ----
        mm256(Wt2, slds, &flags[0][0], q, g0, acc);
        __syncthreads();
        {
            int any = lif4x4(m2, acc, (const float*)&b2q, 0.88f, slds, j0, g0);
            unsigned long long bl = __ballot(any);
            if (lane == 0) flags[1][wvid] = (bl != 0ULL) ? 1 : 0;
        }
        __syncthreads();

        // ---- layer 3 ----
        mm256(Wt3, slds, &flags[1][0], q, g0, acc);
        __syncthreads();
        {
            int any = lif4x4(m3, acc, (const float*)&b3q, 0.86f, slds, j0, g0);
            unsigned long long bl = __ballot(any);
            if (lane == 0) flags[2][wvid] = (bl != 0ULL) ? 1 : 0;
        }
        __syncthreads();

        // ---- layer 4 ----
        mm256(Wt4, slds, &flags[2][0], q, g0, acc);
        __syncthreads();
        {
            int any = lif4x4(m4, acc, (const float*)&b4q, 0.84f, slds, j0, g0);
            unsigned long long bl = __ballot(any);
            if (lane == 0) flags[3][wvid] = (bl != 0ULL) ? 1 : 0;
        }
        __syncthreads();

        // ---- layer 5: 256 -> 128, thread owns (2 j, 4 g) ----
        {
            float acc5[8];
#pragma unroll
            for (int k = 0; k < 8; ++k) acc5[k] = 0.f;
            int4 f = *(const int4*)&flags[3][0];
            if (f.x | f.y | f.z | f.w) {
                const float2* wp5 = (const float2*)Wt5 + q;   // Wt5[i*128 + 2q]
#pragma unroll 4
                for (int i = 0; i < 256; ++i) {
                    float2 w2 = wp5[i * 64];
                    float4 s4 = *(const float4*)&slds[i][g0];
                    acc5[0] = fmaf(s4.x, w2.x, acc5[0]);
                    acc5[1] = fmaf(s4.y, w2.x, acc5[1]);
                    acc5[2] = fmaf(s4.z, w2.x, acc5[2]);
                    acc5[3] = fmaf(s4.w, w2.x, acc5[3]);
                    acc5[4] = fmaf(s4.x, w2.y, acc5[4]);
                    acc5[5] = fmaf(s4.y, w2.y, acc5[5]);
                    acc5[6] = fmaf(s4.z, w2.y, acc5[6]);
                    acc5[7] = fmaf(s4.w, w2.y, acc5[7]);
                }
            }
            __syncthreads();
            int any = 0;
#pragma unroll
            for (int jj = 0; jj < 2; ++jj) {
                float4 sp;
#pragma unroll
                for (int gg = 0; gg < 4; ++gg) {
                    int k = jj * 4 + gg;
                    float cur = acc5[k] + ((const float*)&b5q)[jj];
                    float mp  = m5[k];
                    float mn  = fmaf(0.82f, mp, cur) - (mp > 1.f ? 1.f : 0.f);
                    m5[k] = mn;
                    int s1 = (mn > 1.f);
                    any |= s1;
                    ((float*)&sp)[gg] = s1 ? 1.f : 0.f;
                }
                *(float4*)&slds[q * 2 + jj][g0] = sp;
            }
            unsigned long long bl = __ballot(any);
            if (lane == 0) flags[4][wvid] = (bl != 0ULL) ? 1 : 0;
        }
        __syncthreads();

        // ---- layer 6: 128 -> 3, accumulate over steps ----
        {
            int4 f = *(const int4*)&flags[4][0];
            if (t < 48) {
                float ov = b6v;
                if (f.x | f.y | f.z | f.w) {
                    float s = 0.f;
#pragma unroll 4
                    for (int i = 0; i < 128; ++i) s = fmaf(slds[i][og], w6l[ok][i], s);
                    ov = s + b6v;
                }
                accout += ov;
            }
        }
    }

    if (t < 48) out[(s0 + og) * 3 + ok] = accout / 15.0f;
}

extern "C" void kernel_launch(void* const* d_in, const int* in_sizes, int n_in,
                              void* d_out, int out_size, void* d_ws, size_t ws_size,
                              hipStream_t stream) {
    const float* x  = (const float*)d_in[0];
    const float* W1 = (const float*)d_in[1];
    const float* b1 = (const float*)d_in[2];
    const float* W2 = (const float*)d_in[3];
    const float* b2 = (const float*)d_in[4];
    const float* W3 = (const float*)d_in[5];
    const float* b3 = (const float*)d_in[6];
    const float* W4 = (const float*)d_in[7];
    const float* b4 = (const float*)d_in[8];
    const float* W5 = (const float*)d_in[9];
    const float* b5 = (const float*)d_in[10];
    const float* W6 = (const float*)d_in[11];
    const float* b6 = (const float*)d_in[12];
    float* out = (float*)d_out;

    float* ws  = (float*)d_ws;
    float* Wt2 = ws;                 // [256][256]
    float* Wt3 = Wt2 + 65536;
    float* Wt4 = Wt3 + 65536;
    float* Wt5 = Wt4 + 65536;        // [256][128]
    size_t need = (size_t)(65536 * 3 + 32768) * sizeof(float);
    if (ws_size < need) return;

    k_transpose<<<dim3(8, 8), 256, 0, stream>>>(W2, Wt2, 256, 256);
    k_transpose<<<dim3(8, 8), 256, 0, stream>>>(W3, Wt3, 256, 256);
    k_transpose<<<dim3(8, 8), 256, 0, stream>>>(W4, Wt4, 256, 256);
    k_transpose<<<dim3(8, 4), 256, 0, stream>>>(W5, Wt5, 128, 256);
    k_snn<<<B_SZ / 16, 256, 0, stream>>>(x, W1, b1, Wt2, b2, Wt3, b3,
                                         Wt4, b4, Wt5, b5, W6, b6, out);
}